// Round 3
// baseline (1133.128 us; speedup 1.0000x reference)
//
#include <hip/hip_runtime.h>

#define KN  50
#define NM  10          // MBON == DAN == 10
#define LPB 16          // lanes per batch element
#define WSTRIDE 42      // dwords per lane of LDS wct slab (pad 40->42: bank stride 10 -> 2-way only)

typedef float v2f __attribute__((ext_vector_type(2)));

// mov_dpp(old=0,bound_ctrl=1) + fadd; GCNDPPCombine fuses into v_add_f32_dpp
template <int CTRL>
__device__ __forceinline__ float dpp_add(float x) {
  return x + __int_as_float(
      __builtin_amdgcn_update_dpp(0, __float_as_int(x), CTRL, 0xF, 0xF, true));
}

__device__ __forceinline__ float rowsum16(float x) {
  x = dpp_add<0x121>(x);   // row_ror:1
  x = dpp_add<0x122>(x);   // row_ror:2
  x = dpp_add<0x124>(x);   // row_ror:4
  x = dpp_add<0x128>(x);   // row_ror:8
  return x;
}

__device__ __forceinline__ float bcast(int idx4, float x) {
  return __int_as_float(__builtin_amdgcn_ds_bpermute(idx4, __float_as_int(x)));
}

extern "C" __global__ void __launch_bounds__(256)
fly_kernel(const float* __restrict__ odor,    // [T,B,3]
           const float* __restrict__ ctxp,    // [T,B,1]
           const float* __restrict__ pn_w,    // [B,3,KN]
           const float* __restrict__ kn_b,    // [KN]
           const float* __restrict__ apl_w,   // [KN,1]
           const float* __restrict__ apl_b,   // [1]
           const float* __restrict__ mdw_g,   // mbon_dan_weight [DAN,MBON]
           const float* __restrict__ mbon_b,  // [MBON]
           const float* __restrict__ dmw_g,   // dan_mbon_weight [MBON,DAN]
           const float* __restrict__ ddw_g,   // dan_dan_weight [DAN,DAN]
           const float* __restrict__ dcw_g,   // dan_context_weight [1,DAN]
           const float* __restrict__ dan_b,   // [DAN]
           const float* __restrict__ decW,    // [2,MBON]
           const float* __restrict__ decb,    // [2]
           const float* __restrict__ kcw0,    // [B,KN,MBON]
           const float* __restrict__ wact0,   // [B,KN,MBON]
           float* __restrict__ out,           // [T,B,2]
           int B, int T)
{
  __shared__ float smem[256 * WSTRIDE];       // lane-private wct slabs; no barriers needed

  const int tid   = threadIdx.x;
  const int j     = tid & (LPB - 1);
  const int jhalf = j >> 1;
  const int jodd  = j & 1;
  const int b     = blockIdx.x * (256 / LPB) + (tid >> 4);
  if (b >= B) return;

  const int base4 = (tid & 48) << 2;          // byte idx of lane 0 of this 16-lane group
  v2f* __restrict__ wlds = reinterpret_cast<v2f*>(&smem[tid * WSTRIDE]); // 8B aligned (42*4=168)

  // ---- persistent plastic kcw in VGPRs, wct in LDS ----
  // phantom rows k>=KN carry all-zero weights/state -> provably stay zero (apl>=0)
  v2f kcw[4][5];
  #pragma unroll
  for (int i = 0; i < 4; ++i) {
    const int k = j + 16 * i;
    if (k < KN) {
      const v2f* a = reinterpret_cast<const v2f*>(kcw0  + ((size_t)b * KN + k) * NM);
      const v2f* w = reinterpret_cast<const v2f*>(wact0 + ((size_t)b * KN + k) * NM);
      #pragma unroll
      for (int h = 0; h < 5; ++h) { kcw[i][h] = a[h]; wlds[i * 5 + h] = w[h]; }
    } else {
      v2f zz; zz.x = 0.f; zz.y = 0.f;
      #pragma unroll
      for (int h = 0; h < 5; ++h) { kcw[i][h] = zz; wlds[i * 5 + h] = zz; }
    }
  }

  // ---- packed per-row constants: pair q holds rows i=2q (.x), i=2q+1 (.y) ----
  v2f pw0v[2], pw1v[2], pw2v[2], knbv[2], awv[2], kcnv[2], lkcv[2];
  #pragma unroll
  for (int q = 0; q < 2; ++q) {
    float c0[2], c1[2], c2[2], cb[2], ca[2];
    #pragma unroll
    for (int h2 = 0; h2 < 2; ++h2) {
      const int k = j + 16 * (2 * q + h2);
      if (k < KN) {
        c0[h2] = pn_w[((size_t)b * 3 + 0) * KN + k];
        c1[h2] = pn_w[((size_t)b * 3 + 1) * KN + k];
        c2[h2] = pn_w[((size_t)b * 3 + 2) * KN + k];
        cb[h2] = kn_b[k];
        ca[h2] = apl_w[k];
      } else { c0[h2]=c1[h2]=c2[h2]=cb[h2]=ca[h2]=0.f; }
    }
    pw0v[q].x = c0[0]; pw0v[q].y = c0[1];
    pw1v[q].x = c1[0]; pw1v[q].y = c1[1];
    pw2v[q].x = c2[0]; pw2v[q].y = c2[1];
    knbv[q].x = cb[0]; knbv[q].y = cb[1];
    awv[q].x  = ca[0]; awv[q].y  = ca[1];
    kcnv[q].x = 0.f; kcnv[q].y = 0.f;
    lkcv[q].x = 0.f; lkcv[q].y = 0.f;
  }

  // ---- per-column (m == j) small weights; lanes j>=10 hold zeros ----
  v2f   mdw2[5], ddw2[5];
  float dmw[NM];
  float cw = 0.f, db_ = 0.f, mb_ = 0.f, dw0 = 0.f, dw1 = 0.f;
  #pragma unroll
  for (int h = 0; h < 5; ++h) { mdw2[h].x = 0.f; mdw2[h].y = 0.f; ddw2[h].x = 0.f; ddw2[h].y = 0.f; }
  #pragma unroll
  for (int m = 0; m < NM; ++m) dmw[m] = 0.f;
  if (j < NM) {
    #pragma unroll
    for (int h = 0; h < 5; ++h) {
      mdw2[h].x = mdw_g[(2*h)   * NM + j];  mdw2[h].y = mdw_g[(2*h+1) * NM + j];
      ddw2[h].x = ddw_g[(2*h)   * NM + j];  ddw2[h].y = ddw_g[(2*h+1) * NM + j];
    }
    #pragma unroll
    for (int m = 0; m < NM; ++m) dmw[m] = dmw_g[m * NM + j];
    cw  = dcw_g[j];
    db_ = dan_b[j];
    mb_ = mbon_b[j];
    dw0 = decW[j];
    dw1 = decW[NM + j];
  }
  const float aplb = apl_b[0];
  const float db0 = decb[0], db1 = decb[1];
  const float ALPHA = (float)(0.5 / 5.5);     // DT/(DT+RC)

  // ---- recurrent small state ----
  float apl = 0.f, mbon_m = 0.f, dan_m = 0.f;
  v2f dvec2[5], ldv2[5];
  #pragma unroll
  for (int h = 0; h < 5; ++h) { dvec2[h].x = 0.f; dvec2[h].y = 0.f; ldv2[h].x = 0.f; ldv2[h].y = 0.f; }

  // pointer-increment addressing (no per-step index math)
  const float* op = odor + (size_t)b * 3;
  const float* cp = ctxp + b;
  float* outp = out + (size_t)b * 2;
  const size_t B3 = (size_t)B * 3;

  for (int t = 0; t < T; ++t) {
    const float o0 = op[0], o1 = op[1], o2 = op[2];  op += B3;
    const float cx = *cp;                            cp += B;

    // --- Kenyon update (packed row-pairs) + kc_value/apl partial sums ---
    float kns[4], lks[4];
    v2f psum2; psum2.x = 0.f; psum2.y = 0.f;
    v2f p2[5];
    #pragma unroll
    for (int h = 0; h < 5; ++h) { p2[h].x = 0.f; p2[h].y = 0.f; }

    #pragma unroll
    for (int q = 0; q < 2; ++q) {
      v2f pv  = pw0v[q] * o0 + pw1v[q] * o1 + pw2v[q] * o2;
      v2f arg = pv + knbv[q] - apl;
      v2f r; r.x = fmaxf(arg.x, 0.f); r.y = fmaxf(arg.y, 0.f);
      v2f kn = 0.5f * (kcnv[q] + r);                 // dt_tau = 0.5
      kcnv[q] = kn;
      lkcv[q] = lkcv[q] + ALPHA * (kn - lkcv[q]);    // low_kc_n (new kc_n)
      psum2 += kn * awv[q];
      kns[2*q] = kn.x;      kns[2*q+1] = kn.y;
      lks[2*q] = lkcv[q].x; lks[2*q+1] = lkcv[q].y;
    }
    #pragma unroll
    for (int i = 0; i < 4; ++i) {
      #pragma unroll
      for (int h = 0; h < 5; ++h) p2[h] += kns[i] * kcw[i][h];  // vs pre-update kc_w
    }

    const float psum = rowsum16(psum2.x + psum2.y);
    #pragma unroll
    for (int h = 0; h < 5; ++h) {
      p2[h].x = rowsum16(p2[h].x);
      p2[h].y = rowsum16(p2[h].y);
    }

    apl = 0.5f * apl + 0.5f * fmaxf(psum + aplb, 0.f);

    // select this lane's column value
    v2f rsel = p2[0];
    #pragma unroll
    for (int h = 1; h < 5; ++h) rsel = (jhalf == h) ? p2[h] : rsel;
    const float kcv = jodd ? rsel.y : rsel.x;

    // --- MBON (column j): dan_mod uses PREVIOUS dan ---
    v2f s2 = dvec2[0] * mdw2[0];
    #pragma unroll
    for (int e = 1; e < 5; ++e) s2 += dvec2[e] * mdw2[e];
    const float s = s2.x + s2.y;
    const float dmod = 1.f / (1.f + __expf(-s));
    mbon_m = 0.5f * mbon_m + 0.5f * dmod * fmaxf(kcv + mb_, 0.f);

    // --- DAN (column j): previous dan + new mbon (fused broadcast) ---
    v2f dp2 = dvec2[0] * ddw2[0];
    #pragma unroll
    for (int e = 1; e < 5; ++e) dp2 += dvec2[e] * ddw2[e];
    float dp = dp2.x + dp2.y + fmaf(cx, cw, db_);
    #pragma unroll
    for (int m = 0; m < NM; ++m)
      dp = fmaf(bcast(base4 + 4 * m, mbon_m), dmw[m], dp);
    dan_m = 0.5f * dan_m + 0.5f * fmaxf(dp, 0.f);

    // broadcast new dan; update low_dan
    #pragma unroll
    for (int e = 0; e < 5; ++e) {
      dvec2[e].x = bcast(base4 + 8 * e,     dan_m);
      dvec2[e].y = bcast(base4 + 8 * e + 4, dan_m);
      ldv2[e] += ALPHA * (dvec2[e] - ldv2[e]);      // low_dan_n (new dan)
    }

    // --- decoder output ---
    const float q0 = rowsum16(mbon_m * dw0) + db0;
    const float q1 = rowsum16(mbon_m * dw1) + db1;
    if (j == 0) {
      float2 st; st.x = q0; st.y = q1;
      *reinterpret_cast<float2*>(outp) = st;
    }
    outp += (size_t)B * 2;

    // --- plasticity: kc_w decays toward OLD wact, then wact += DT*syn (wct in LDS) ---
    #pragma unroll
    for (int i = 0; i < 4; ++i) {
      const float kh  =  0.5f * kns[i];    // DT * kc_n
      const float nlh = -0.5f * lks[i];    // -DT * low_kc_n
      v2f w[5];
      #pragma unroll
      for (int h = 0; h < 5; ++h) w[h] = wlds[i * 5 + h];
      #pragma unroll
      for (int h = 0; h < 5; ++h) {
        kcw[i][h] = 0.75f * kcw[i][h] + 0.25f * w[h];       // uses wact BEFORE syn
        wlds[i * 5 + h] = w[h] + kh * ldv2[h] + nlh * dvec2[h];  // wact_n
      }
    }
  }
}

extern "C" void kernel_launch(void* const* d_in, const int* in_sizes, int n_in,
                              void* d_out, int out_size, void* d_ws, size_t ws_size,
                              hipStream_t stream) {
  const float* odor   = (const float*)d_in[0];
  const float* ctx    = (const float*)d_in[1];
  const float* pn_w   = (const float*)d_in[2];
  const float* kn_b   = (const float*)d_in[3];
  const float* apl_w  = (const float*)d_in[4];
  const float* apl_b  = (const float*)d_in[5];
  const float* mdw    = (const float*)d_in[6];
  const float* mbon_b = (const float*)d_in[7];
  const float* dmw    = (const float*)d_in[8];
  const float* ddw    = (const float*)d_in[9];
  const float* dcw    = (const float*)d_in[10];
  const float* dan_b  = (const float*)d_in[11];
  const float* decW   = (const float*)d_in[12];
  const float* decb   = (const float*)d_in[13];
  const float* kcw0   = (const float*)d_in[14];
  const float* wact0  = (const float*)d_in[15];
  float* out = (float*)d_out;

  const int B = in_sizes[14] / (KN * NM);   // kc_weight0 is [B,50,10]
  const int T = in_sizes[0] / (B * 3);      // odor is [T,B,3]

  const int batches_per_block = 256 / LPB;  // 16
  dim3 grid((B + batches_per_block - 1) / batches_per_block);
  dim3 block(256);
  hipLaunchKernelGGL(fly_kernel, grid, block, 0, stream,
                     odor, ctx, pn_w, kn_b, apl_w, apl_b,
                     mdw, mbon_b, dmw, ddw, dcw, dan_b,
                     decW, decb, kcw0, wact0, out, B, T);
}